// Round 3
// baseline (1039.656 us; speedup 1.0000x reference)
//
#include <hip/hip_runtime.h>
#include <stdint.h>

// Problem constants
#define B_ 2
#define N_ 25
#define S_ 4096
#define I_ 63
#define W_ 256
#define D_ 8
#define Z_ 16

typedef float f32x4 __attribute__((ext_vector_type(4)));
typedef __bf16 bf16x8 __attribute__((ext_vector_type(8)));

// ---- bf16 split helpers (RNE) ----
__device__ __forceinline__ unsigned short f2bf(float x) {
  unsigned int u = __float_as_uint(x);
  unsigned int r = (u + 0x7fffu + ((u >> 16) & 1u)) >> 16;
  return (unsigned short)r;
}
__device__ __forceinline__ float bf2f(unsigned short h) {
  return __uint_as_float(((unsigned int)h) << 16);
}

// =====================================================================
// Prep: transpose [K][V] -> [V][Kp] (k-contiguous rows), split fp32 into
// bf16 hi/lo. in: [nmat][K][V]; out_hi/out_lo: [nmat][V][Kp]. Zero-pads
// k in [K,Kp).
// =====================================================================
__global__ void prep_tr(const float* __restrict__ in,
                        unsigned short* __restrict__ oh,
                        unsigned short* __restrict__ ol,
                        int K, int V, int Kp, int tiles_k, int tiles_v) {
  __shared__ float tile[64][65];
  int tpm = tiles_k * tiles_v;
  int m  = blockIdx.x / tpm;
  int tt = blockIdx.x - m * tpm;
  int tk = tt / tiles_v, tv = tt - tk * tiles_v;
  int k0 = tk * 64, v0 = tv * 64;
  const float* src = in + (size_t)m * K * V;
  int c  = threadIdx.x & 63;
  int r0 = threadIdx.x >> 6;
#pragma unroll
  for (int i = 0; i < 16; ++i) {
    int r = i * 4 + r0;
    int k = k0 + r, v = v0 + c;
    tile[r][c] = (k < K && v < V) ? src[(size_t)k * V + v] : 0.0f;
  }
  __syncthreads();
  unsigned short* dh = oh + (size_t)m * V * Kp;
  unsigned short* dl = ol + (size_t)m * V * Kp;
#pragma unroll
  for (int i = 0; i < 16; ++i) {
    int r = i * 4 + r0;
    int v = v0 + r, k = k0 + c;
    if (v < V && k < Kp) {
      float val = tile[c][r];
      unsigned short hi = f2bf(val);
      unsigned short lo = f2bf(val - bf2f(hi));
      dh[(size_t)v * Kp + k] = hi;
      dl[(size_t)v * Kp + k] = lo;
    }
  }
}

// =====================================================================
// Fused MLP main kernel, v2.
// Grid: 3200 blocks = 25 n-groups x 128 token-tiles (64 tokens each).
// Block: 512 threads (8 waves). Wave w owns output cols [w*32, w*32+32)
// for all 64 tokens (wave tile 64x32, acc[4][2] f32x4).
// B operand: NEVER staged in LDS — loaded global->VGPR as MFMA fragments
// (lane pattern col=lane&15, k=(lane>>4)*8), register double-buffered one
// 32-wide K-chunk ahead. No barriers / no vmcnt(0) in the K-loop.
// LDS: Ah/Al [64][256] bf16 hi/lo, XOR-swizzled, 64 KB static total ->
// 2 blocks/CU (16 waves) with __launch_bounds__(512,4) (VGPR<=128).
// A swizzle: elem(tok,k) = tok*256 + (((k>>3) ^ (tok&31))<<3) + (k&7)
// Barriers: 2 per layer (Ah/Al write-after-read fence).
// =====================================================================
__global__ __launch_bounds__(512, 4) void mlp_fused(
    const float* __restrict__ x, const float* __restrict__ b0,
    const float* __restrict__ bmid, const float* __restrict__ blast,
    const unsigned short* __restrict__ wt0h, const unsigned short* __restrict__ wt0l,
    const unsigned short* __restrict__ wtmh, const unsigned short* __restrict__ wtml,
    const unsigned short* __restrict__ wtlh, const unsigned short* __restrict__ wtll,
    float* __restrict__ out) {
  __shared__ unsigned short Ah[64 * 256];
  __shared__ unsigned short Al[64 * 256];

  const int tid  = threadIdx.x;
  const int lane = tid & 63;
  const int wave = tid >> 6;
  const int lrow = lane & 15;   // MFMA row/col-within-16
  const int lk   = lane >> 4;   // MFMA k-octet
  const int koff = lk * 8;

  // XCD-chunked bijective swizzle (3200 = 8*400): same-n blocks share an XCD L2
  const int bid = blockIdx.x;
  const int w   = (bid & 7) * 400 + (bid >> 3);
  const int n   = w >> 7;        // 0..24 (128 blocks per n)
  const int t   = w & 127;
  const int bb  = t >> 6;        // batch
  const int s0  = (t & 63) * 64; // seq offset

  // ---- stage x (fp32 -> hi/lo bf16) into Ah/Al, k padded to 64 ----
  {
    const float* xp = x + (((size_t)bb * N_ + n) * S_ + s0) * I_;
#pragma unroll
    for (int i = 0; i < 8; ++i) {
      int e = i * 512 + tid;      // 0..4095
      int tok = e >> 6, k = e & 63;
      float val = (k < I_) ? xp[tok * I_ + k] : 0.0f;
      unsigned short hi = f2bf(val);
      unsigned short lo = f2bf(val - bf2f(hi));
      int off = tok * 256 + ((((k >> 3) ^ (tok & 31)) << 3) | (k & 7));
      Ah[off] = hi;
      Al[off] = lo;
    }
  }
  __syncthreads();

  const int cbase = wave * 32 + lrow;   // this wave's B-column for lane
  f32x4 acc[4][2];

  // ---- layers 0..6 (input layer K=64(pad) + 6 mid layers K=256) ----
#pragma unroll 1
  for (int l = 0; l < 7; ++l) {
    const unsigned short *wh, *wl;
    const float* bias;
    int rowlen, nkc;
    if (l == 0) {
      wh = wt0h + (size_t)n * (W_ * 64);
      wl = wt0l + (size_t)n * (W_ * 64);
      bias = b0 + n * W_;
      rowlen = 64; nkc = 2;
    } else {
      size_t o = ((size_t)(l - 1) * N_ + n) * ((size_t)W_ * W_);
      wh = wtmh + o;
      wl = wtml + o;
      bias = bmid + ((size_t)(l - 1) * N_ + n) * W_;
      rowlen = W_; nkc = 8;
    }
#pragma unroll
    for (int i = 0; i < 4; ++i)
#pragma unroll
      for (int j = 0; j < 2; ++j)
        acc[i][j] = (f32x4){0.f, 0.f, 0.f, 0.f};

    // B-fragment loader: global -> VGPR, MFMA layout directly
    auto loadB = [&](bf16x8 (&dst)[2][2], int kc) {
#pragma unroll
      for (int vt = 0; vt < 2; ++vt) {
        size_t ro = (size_t)(cbase + vt * 16) * rowlen + kc * 32 + koff;
        dst[vt][0] = *(const bf16x8*)(wh + ro);
        dst[vt][1] = *(const bf16x8*)(wl + ro);
      }
    };
    // one K-chunk of MFMAs (A from LDS, B from regs)
    auto stepK = [&](bf16x8 (&buf)[2][2], int kc) {
      bf16x8 ahf[4], alf[4];
#pragma unroll
      for (int rt = 0; rt < 4; ++rt) {
        int tok = rt * 16 + lrow;
        int off = tok * 256 + (((kc * 4 + lk) ^ (tok & 31)) << 3);
        ahf[rt] = *(const bf16x8*)(Ah + off);
        alf[rt] = *(const bf16x8*)(Al + off);
      }
#pragma unroll
      for (int vt = 0; vt < 2; ++vt)
#pragma unroll
        for (int rt = 0; rt < 4; ++rt) {
          acc[rt][vt] = __builtin_amdgcn_mfma_f32_16x16x32_bf16(ahf[rt], buf[vt][0], acc[rt][vt], 0, 0, 0);
          acc[rt][vt] = __builtin_amdgcn_mfma_f32_16x16x32_bf16(alf[rt], buf[vt][0], acc[rt][vt], 0, 0, 0);
          acc[rt][vt] = __builtin_amdgcn_mfma_f32_16x16x32_bf16(ahf[rt], buf[vt][1], acc[rt][vt], 0, 0, 0);
        }
    };

    bf16x8 bufA[2][2], bufB[2][2];
    loadB(bufA, 0);
#pragma unroll 1
    for (int kc = 0; kc < nkc; kc += 2) {
      if (kc + 1 < nkc) loadB(bufB, kc + 1);
      stepK(bufA, kc);
      if (kc + 2 < nkc) loadB(bufA, kc + 2);
      if (kc + 1 < nkc) stepK(bufB, kc + 1);
    }

    // ---- epilogue: bias + ReLU + hi/lo split -> Ah/Al ----
    __syncthreads();   // all A reads (block-wide) complete
#pragma unroll
    for (int vt = 0; vt < 2; ++vt) {
      int col = wave * 32 + vt * 16 + lrow;
      float bv = bias[col];
#pragma unroll
      for (int rt = 0; rt < 4; ++rt) {
        f32x4 cfr = acc[rt][vt];
#pragma unroll
        for (int r = 0; r < 4; ++r) {
          int tok = rt * 16 + lk * 4 + r;  // C layout: row=(lane>>4)*4+reg
          float val = fmaxf(cfr[r] + bv, 0.0f);
          unsigned short hi = f2bf(val);
          unsigned short lo = f2bf(val - bf2f(hi));
          int off = tok * 256 + ((((col >> 3) ^ (tok & 31)) << 3) | (col & 7));
          Ah[off] = hi;
          Al[off] = lo;
        }
      }
    }
    __syncthreads();
  }

  // ---- last layer: K=256 -> Z=16, no ReLU, fp32 out. Waves 0..3 only. ----
  if (wave < 4) {
    const unsigned short* wh = wtlh + (size_t)n * (Z_ * W_);
    const unsigned short* wl = wtll + (size_t)n * (Z_ * W_);
    const int rt = wave;             // row-tile: tokens rt*16..rt*16+15
    f32x4 accL = (f32x4){0.f, 0.f, 0.f, 0.f};
#pragma unroll
    for (int kc = 0; kc < 8; ++kc) {
      size_t ro = (size_t)lrow * W_ + kc * 32 + koff;   // col = lrow (<16)
      bf16x8 bh = *(const bf16x8*)(wh + ro);
      bf16x8 bl = *(const bf16x8*)(wl + ro);
      int tok = rt * 16 + lrow;
      int aoff = tok * 256 + (((kc * 4 + lk) ^ (tok & 31)) << 3);
      bf16x8 ahf = *(const bf16x8*)(Ah + aoff);
      bf16x8 alf = *(const bf16x8*)(Al + aoff);
      accL = __builtin_amdgcn_mfma_f32_16x16x32_bf16(ahf, bh, accL, 0, 0, 0);
      accL = __builtin_amdgcn_mfma_f32_16x16x32_bf16(alf, bh, accL, 0, 0, 0);
      accL = __builtin_amdgcn_mfma_f32_16x16x32_bf16(ahf, bl, accL, 0, 0, 0);
    }
    float bv = blast[n * Z_ + lrow];
    float* op = out + (((size_t)bb * N_ + n) * S_ + s0) * Z_;
#pragma unroll
    for (int r = 0; r < 4; ++r) {
      int tok = rt * 16 + lk * 4 + r;
      op[(size_t)tok * Z_ + lrow] = accL[r] + bv;
    }
  }
}

// =====================================================================
// Fallback: pure-fp32 vector-ALU path, no workspace. Correct but slow.
// Fires only if ws_size is insufficient.
// =====================================================================
__global__ __launch_bounds__(256) void mlp_fallback(
    const float* __restrict__ x, const float* __restrict__ W0,
    const float* __restrict__ b0, const float* __restrict__ Wmid,
    const float* __restrict__ bmid, const float* __restrict__ Wlast,
    const float* __restrict__ blast, float* __restrict__ out) {
  __shared__ float h[64][256];
  const int g  = blockIdx.x;
  const int n  = g >> 7;
  const int t  = g & 127;
  const int bb = t >> 6;
  const int s0 = (t & 63) * 64;
  const int v  = threadIdx.x;

  const float* xp = x + (((size_t)bb * N_ + n) * S_ + s0) * I_;
  float r[64];
  {
    const float* w = W0 + (size_t)n * I_ * W_;
    float bv = b0[n * W_ + v];
#pragma unroll 8
    for (int i = 0; i < 64; ++i) r[i] = bv;
    for (int k = 0; k < I_; ++k) {
      float wv = w[(size_t)k * W_ + v];
#pragma unroll
      for (int i = 0; i < 64; ++i) r[i] += xp[(size_t)i * I_ + k] * wv;
    }
#pragma unroll
    for (int i = 0; i < 64; ++i) h[i][v] = fmaxf(r[i], 0.f);
    __syncthreads();
  }
  for (int d = 0; d < D_ - 2; ++d) {
    const float* w = Wmid + ((size_t)d * N_ + n) * W_ * W_;
    float bv = bmid[((size_t)d * N_ + n) * W_ + v];
#pragma unroll 8
    for (int i = 0; i < 64; ++i) r[i] = bv;
    for (int k = 0; k < W_; ++k) {
      float wv = w[(size_t)k * W_ + v];
#pragma unroll
      for (int i = 0; i < 64; ++i) r[i] += h[i][k] * wv;
    }
    __syncthreads();
#pragma unroll
    for (int i = 0; i < 64; ++i) h[i][v] = fmaxf(r[i], 0.f);
    __syncthreads();
  }
  if (v < Z_) {
    const float* w = Wlast + (size_t)n * W_ * Z_;
    float bv = blast[n * Z_ + v];
#pragma unroll 8
    for (int i = 0; i < 64; ++i) r[i] = bv;
    for (int k = 0; k < W_; ++k) {
      float wv = w[(size_t)k * Z_ + v];
#pragma unroll
      for (int i = 0; i < 64; ++i) r[i] += h[i][k] * wv;
    }
    float* op = out + (((size_t)bb * N_ + n) * S_ + s0) * Z_;
#pragma unroll
    for (int i = 0; i < 64; ++i) op[(size_t)i * Z_ + v] = r[i];
  }
}

// =====================================================================
extern "C" void kernel_launch(void* const* d_in, const int* in_sizes, int n_in,
                              void* d_out, int out_size, void* d_ws, size_t ws_size,
                              hipStream_t stream) {
  const float* x     = (const float*)d_in[0];
  const float* W0    = (const float*)d_in[1];
  const float* b0    = (const float*)d_in[2];
  const float* Wmid  = (const float*)d_in[3];
  const float* bmid  = (const float*)d_in[4];
  const float* Wlast = (const float*)d_in[5];
  const float* blast = (const float*)d_in[6];
  float* out = (float*)d_out;
  (void)in_sizes; (void)n_in; (void)out_size;

  const size_t n_wt0 = (size_t)N_ * W_ * 64;                 // 409,600
  const size_t n_wtm = (size_t)(D_ - 2) * N_ * W_ * W_;      // 9,830,400
  const size_t n_wtl = (size_t)N_ * Z_ * W_;                 // 102,400
  const size_t need_bytes = 2 * (n_wt0 + n_wtm + n_wtl) * sizeof(unsigned short);

  if (ws_size >= need_bytes) {
    unsigned short* ws   = (unsigned short*)d_ws;
    unsigned short* wt0h = ws;
    unsigned short* wt0l = wt0h + n_wt0;
    unsigned short* wtmh = wt0l + n_wt0;
    unsigned short* wtml = wtmh + n_wtm;
    unsigned short* wtlh = wtml + n_wtm;
    unsigned short* wtll = wtlh + n_wtl;

    // weight prep every call (ws re-poisoned before every timed launch)
    prep_tr<<<25 * 4, 256, 0, stream>>>(W0, wt0h, wt0l, I_, W_, 64, 1, 4);
    prep_tr<<<150 * 16, 256, 0, stream>>>(Wmid, wtmh, wtml, W_, W_, W_, 4, 4);
    prep_tr<<<25 * 4, 256, 0, stream>>>(Wlast, wtlh, wtll, W_, Z_, W_, 4, 1);

    mlp_fused<<<3200, 512, 0, stream>>>(x, b0, bmid, blast,
                                        wt0h, wt0l, wtmh, wtml, wtlh, wtll, out);
  } else {
    mlp_fallback<<<25 * 128, 256, 0, stream>>>(x, W0, b0, Wmid, bmid, Wlast, blast, out);
  }
}